// Round 10
// baseline (246.079 us; speedup 1.0000x reference)
//
#include <hip/hip_runtime.h>
#include <hip/hip_bf16.h>

typedef __hip_bfloat16 bf16;
typedef __attribute__((ext_vector_type(8))) short short8;
typedef __attribute__((ext_vector_type(4))) short shortx4;
typedef __attribute__((ext_vector_type(4))) float floatx4;
typedef __attribute__((ext_vector_type(4))) int intx4;

#define MFMA16(a, b, c) __builtin_amdgcn_mfma_f32_16x16x32_bf16((a), (b), (c), 0, 0, 0)
#define EXP2(x) __builtin_amdgcn_exp2f(x)

__device__ __forceinline__ short f2s(float v) {
    return __builtin_bit_cast(short, __float2bfloat16(v));
}

// pack two fp32 as truncated bf16 pair {lo, hi} with a single v_perm_b32
__device__ __forceinline__ int packhi(float lo, float hi) {
    return (int)__builtin_amdgcn_perm(__builtin_bit_cast(unsigned, hi),
                                      __builtin_bit_cast(unsigned, lo),
                                      0x07060302u);
}

// convert 8 fp32 (two float4 already in regs) to packed bf16 short8
__device__ __forceinline__ short8 cvt8v(float4 f0, float4 f1) {
    short8 r;
    r[0] = f2s(f0.x); r[1] = f2s(f0.y); r[2] = f2s(f0.z); r[3] = f2s(f0.w);
    r[4] = f2s(f1.x); r[5] = f2s(f1.y); r[6] = f2s(f1.z); r[7] = f2s(f1.w);
    return r;
}

// ---------------------------------------------------------------------------
// Kernel 1: qkv = x @ w_qkv^T, 128x128 tile, LDS ping-pong.
//   q: [bh][n][d] PRE-SCALED by C;  k: [bh][n][d]
//   vt:[bh][d][n j-permuted per 64-tile] (slot u holds logical j = pi(u))
//   ALL epilogues LDS-staged -> 16B coalesced global writes (the direct 2B
//   scatter was ~16x transaction-amplified and dominated the kernel).
// ---------------------------------------------------------------------------
__global__ __launch_bounds__(256) void qkv_gemm(
    const float* __restrict__ x, const float* __restrict__ wq,
    bf16* __restrict__ q, bf16* __restrict__ k, bf16* __restrict__ vt)
{
    __shared__ short pool[20480];               // 40KB: As/Bs dbuf U Qt/Vt
    short (*As)[128][40] = (short(*)[128][40])pool;
    short (*Bs)[128][40] = (short(*)[128][40])(pool + 10240);
    short (*Qt)[144] = (short(*)[144])pool;     // 128 x 128 (+16 pad)
    short (*Vt)[136] = (short(*)[136])pool;
    const int t = threadIdx.x;
    const int bm = blockIdx.x * 128;
    const int be = blockIdx.y * 128;
    const int w = t >> 6, lane = t & 63, lq = lane >> 4, lm = lane & 15;
    const int wr = w >> 1, wc = w & 1;
    const int srow = t >> 1, scol = (t & 1) * 16;
    const float C = 0.18033688011112042f;

    const float* xp = &x[(size_t)(bm + srow) * 512 + scol];
    const float* wp = &wq[(size_t)(be + srow) * 512 + scol];

    float4 xr[4], wr4[4];
    auto issue = [&](int k0) {
        const float4* a = (const float4*)(xp + k0);
        const float4* b = (const float4*)(wp + k0);
        xr[0] = a[0]; xr[1] = a[1]; xr[2] = a[2]; xr[3] = a[3];
        wr4[0] = b[0]; wr4[1] = b[1]; wr4[2] = b[2]; wr4[3] = b[3];
    };
    auto commit = [&](int buf) {
        *(short8*)&As[buf][srow][scol]     = cvt8v(xr[0], xr[1]);
        *(short8*)&As[buf][srow][scol + 8] = cvt8v(xr[2], xr[3]);
        *(short8*)&Bs[buf][srow][scol]     = cvt8v(wr4[0], wr4[1]);
        *(short8*)&Bs[buf][srow][scol + 8] = cvt8v(wr4[2], wr4[3]);
    };

    floatx4 acc[4][4];
#pragma unroll
    for (int i = 0; i < 4; ++i)
#pragma unroll
        for (int j = 0; j < 4; ++j) acc[i][j] = {0.f, 0.f, 0.f, 0.f};

    issue(0);
    commit(0);
    __syncthreads();
    int cur = 0;
    for (int k0 = 0; k0 < 512; k0 += 32) {
        const bool more = (k0 + 32) < 512;
        if (more) issue(k0 + 32);
        short8 af[4], bf[4];
#pragma unroll
        for (int mt = 0; mt < 4; ++mt) af[mt] = *(const short8*)&As[cur][wr * 64 + mt * 16 + lm][lq * 8];
#pragma unroll
        for (int nt = 0; nt < 4; ++nt) bf[nt] = *(const short8*)&Bs[cur][wc * 64 + nt * 16 + lm][lq * 8];
#pragma unroll
        for (int mt = 0; mt < 4; ++mt)
#pragma unroll
            for (int nt = 0; nt < 4; ++nt)
                acc[mt][nt] = MFMA16(af[mt], bf[nt], acc[mt][nt]);
        if (more) {
            commit(cur ^ 1);
            __syncthreads();
        }
        cur ^= 1;
    }

    const int which = be >> 9;     // block-uniform
    __syncthreads();               // all waves done reading As/Bs
    if (which < 2) {
        // q/k: b16-scatter tile into LDS, then 128B-contiguous writeout
        const float scale = (which == 0) ? C : 1.0f;
#pragma unroll
        for (int nt = 0; nt < 4; ++nt) {
            const int e_loc = wc * 64 + nt * 16 + lm;
#pragma unroll
            for (int mt = 0; mt < 4; ++mt)
#pragma unroll
                for (int r = 0; r < 4; ++r)
                    Qt[wr * 64 + mt * 16 + lq * 4 + r][e_loc] = f2s(acc[mt][nt][r] * scale);
        }
        __syncthreads();
        bf16* dst = (which == 0) ? q : k;
        const int tr = t >> 1, th = t & 1;
        const int grow = bm + tr;
        const int b = grow >> 12, n = grow & 4095;
        const int h = ((be + th * 64) & 511) >> 6;
        bf16* p = dst + ((size_t)(b * 8 + h) * 4096 + n) * 64;
#pragma unroll
        for (int c = 0; c < 8; ++c)
            *(intx4*)&p[c * 8] = *(const intx4*)&Qt[tr][th * 64 + c * 8];
    } else {
        // v: stage with pi^-1 applied to n, coalesced writeout along n
#pragma unroll
        for (int nt = 0; nt < 4; ++nt) {
            const int e_loc = wc * 64 + nt * 16 + lm;
#pragma unroll
            for (int mt = 0; mt < 4; ++mt) {
                const int col = wr * 64 + 4 * (mt & 1) + 8 * lq + 32 * (mt >> 1);
                shortx4 v4;
#pragma unroll
                for (int r = 0; r < 4; ++r) v4[r] = f2s(acc[mt][nt][r]);
                *(shortx4*)&Vt[e_loc][col] = v4;
            }
        }
        __syncthreads();
        const int b = bm >> 12, n0 = bm & 4095;
        const int h0 = (be - 1024) >> 6;
        const int row = t >> 1, cb = (t & 1) * 64;
        const int h = h0 + (row >> 6), d = row & 63;
        const size_t gb = ((size_t)(b * 8 + h) * 64 + d) * 4096 + n0 + cb;
#pragma unroll
        for (int c = 0; c < 8; ++c)
            *(intx4*)&vt[gb + c * 8] = *(const intx4*)&Vt[row][cb + c * 8];
    }
}

// ---------------------------------------------------------------------------
// Kernel 2: flash attention, S^T form, no online max, BM=128,
// 2-deep register prefetch + LDS ping-pong (load latency ~2 iters covered).
// ---------------------------------------------------------------------------
__global__ __launch_bounds__(256, 2) void flash_attn(
    const bf16* __restrict__ q, const bf16* __restrict__ k,
    const bf16* __restrict__ vt, bf16* __restrict__ out)
{
    __shared__ short Qs[128][72];
    __shared__ short Ks[2][64][72];
    __shared__ short Vs[2][64][72];   // Vs[.][d][k_phys] (j pre-permuted)
    const int t = threadIdx.x;
    const int i0 = blockIdx.x * 128;
    const int bh = blockIdx.y;
    const int w = t >> 6, lane = t & 63, lq = lane >> 4, lm = lane & 15;
    const floatx4 zero4 = {0.f, 0.f, 0.f, 0.f};

    const size_t nbase = (size_t)bh * 4096 * 64;
    const size_t vbase = (size_t)bh * 64 * 4096;
    const int r0 = t >> 3, c0 = (t & 7) * 8;

#pragma unroll
    for (int it = 0; it < 4; ++it) {
        int off = it * 2048 + t * 8;
        int row = off >> 6, col = off & 63;
        *(intx4*)&Qs[row][col] = *(const intx4*)&q[nbase + (size_t)(i0 + row) * 64 + col];
    }

    intx4 kreg[2][2], vreg[2][2];
    auto issue = [&](int j0n, int s) {
        kreg[s][0] = *(const intx4*)&k[nbase + (size_t)(j0n + r0) * 64 + c0];
        kreg[s][1] = *(const intx4*)&k[nbase + (size_t)(j0n + 32 + r0) * 64 + c0];
        vreg[s][0] = *(const intx4*)&vt[vbase + (size_t)r0 * 4096 + j0n + c0];
        vreg[s][1] = *(const intx4*)&vt[vbase + (size_t)(32 + r0) * 4096 + j0n + c0];
    };
    auto commit = [&](int s, int buf) {
        *(intx4*)&Ks[buf][r0][c0]      = kreg[s][0];
        *(intx4*)&Ks[buf][32 + r0][c0] = kreg[s][1];
        *(intx4*)&Vs[buf][r0][c0]      = vreg[s][0];
        *(intx4*)&Vs[buf][32 + r0][c0] = vreg[s][1];
    };

    issue(0, 0);
    commit(0, 0);
    issue(64, 1);
    __syncthreads();   // covers Qs too
    short8 aq0[2], aq1[2];
#pragma unroll
    for (int g = 0; g < 2; ++g) {
        aq0[g] = *(const short8*)&Qs[g * 64 + w * 16 + lm][lq * 8];
        aq1[g] = *(const short8*)&Qs[g * 64 + w * 16 + lm][32 + lq * 8];
    }

    float l_lane[2] = {0.f, 0.f};
    floatx4 o_acc[2][4];
#pragma unroll
    for (int g = 0; g < 2; ++g)
#pragma unroll
        for (int dt = 0; dt < 4; ++dt) o_acc[g][dt] = zero4;

    for (int i = 0; i < 64; ++i) {
        const int j0 = i * 64;
        const int cur = i & 1;
        if (j0 + 128 < 4096) issue(j0 + 128, cur);

        // S^T = K Q~^T: K A-frags shared across the 2 row-groups
        floatx4 s[2][4];
#pragma unroll
        for (int jt = 0; jt < 4; ++jt) {
            short8 bk0 = *(const short8*)&Ks[cur][jt * 16 + lm][lq * 8];
            short8 bk1 = *(const short8*)&Ks[cur][jt * 16 + lm][32 + lq * 8];
#pragma unroll
            for (int g = 0; g < 2; ++g) {
                s[g][jt] = MFMA16(bk0, aq0[g], zero4);
                s[g][jt] = MFMA16(bk1, aq1[g], s[g][jt]);
            }
        }

        // P = exp2(s), truncated pack; l per-lane
        short8 bp0[2], bp1[2];
#pragma unroll
        for (int g = 0; g < 2; ++g) {
            intx4 pkA, pkB;
#pragma unroll
            for (int jt = 0; jt < 4; ++jt) {
                float e0 = EXP2(s[g][jt][0]);
                float e1 = EXP2(s[g][jt][1]);
                float e2 = EXP2(s[g][jt][2]);
                float e3 = EXP2(s[g][jt][3]);
                l_lane[g] += (e0 + e1) + (e2 + e3);
                if (jt < 2) {
                    pkA[jt * 2]     = packhi(e0, e1);
                    pkA[jt * 2 + 1] = packhi(e2, e3);
                } else {
                    pkB[(jt - 2) * 2]     = packhi(e0, e1);
                    pkB[(jt - 2) * 2 + 1] = packhi(e2, e3);
                }
            }
            bp0[g] = __builtin_bit_cast(short8, pkA);
            bp1[g] = __builtin_bit_cast(short8, pkB);
        }

        // O^T += Vt P^T: V A-frags shared across groups
#pragma unroll
        for (int dt = 0; dt < 4; ++dt) {
            short8 av0 = *(const short8*)&Vs[cur][dt * 16 + lm][lq * 8];
            short8 av1 = *(const short8*)&Vs[cur][dt * 16 + lm][32 + lq * 8];
#pragma unroll
            for (int g = 0; g < 2; ++g) {
                o_acc[g][dt] = MFMA16(av0, bp0[g], o_acc[g][dt]);
                o_acc[g][dt] = MFMA16(av1, bp1[g], o_acc[g][dt]);
            }
        }

        if (j0 + 64 < 4096) {
            commit(cur ^ 1, cur ^ 1);   // tile i+1 -> other buffer
            __syncthreads();
        }
    }

    // epilogue per group: l-reduce, O^T -> LDS transpose -> coalesced writes
    const int b = bh >> 3, h = bh & 7;
    short* Os = (short*)Qs;
    const int obase = w * 1024;
    const int il = lane >> 2, c = (lane & 3) * 16;
#pragma unroll
    for (int g = 0; g < 2; ++g) {
        float l = l_lane[g];
        l += __shfl_xor(l, 16);
        l += __shfl_xor(l, 32);
        const float inv_l = 1.0f / l;
        __syncthreads();
#pragma unroll
        for (int dt = 0; dt < 4; ++dt)
#pragma unroll
            for (int r = 0; r < 4; ++r)
                Os[obase + lm * 64 + dt * 16 + lq * 4 + r] = f2s(o_acc[g][dt][r] * inv_l);
        __syncthreads();
        const int i = i0 + g * 64 + w * 16 + il;
        intx4 v0 = *(const intx4*)&Os[obase + il * 64 + c];
        intx4 v1 = *(const intx4*)&Os[obase + il * 64 + c + 8];
        *(intx4*)&out[((size_t)b * 4096 + i) * 512 + h * 64 + c] = v0;
        *(intx4*)&out[((size_t)b * 4096 + i) * 512 + h * 64 + c + 8] = v1;
    }
}

// ---------------------------------------------------------------------------
// Kernel 3: y = attn_out @ w_out^T + b_out, 128x64 tile, 2-deep prefetch +
// LDS ping-pong.   (fp32 OUTPUT)
// ---------------------------------------------------------------------------
__global__ __launch_bounds__(256) void out_gemm(
    const bf16* __restrict__ a, const float* __restrict__ wo,
    const float* __restrict__ bias, float* __restrict__ y)
{
    __shared__ short As[2][128][40];
    __shared__ short Bs[2][64][40];
    const int t = threadIdx.x;
    const int bm = blockIdx.x * 128;
    const int be = blockIdx.y * 64;
    const int w = t >> 6, lane = t & 63, lq = lane >> 4, lm = lane & 15;
    const int wr = w >> 1, wc = w & 1;
    const int srow = t >> 1, scol = (t & 1) * 16;
    const int brow = t >> 2, bcol = (t & 3) * 8;

    const bf16* ap = &a[(size_t)(bm + srow) * 512 + scol];
    const float* wp = &wo[(size_t)(be + brow) * 512 + bcol];

    intx4 ar[2][2];
    float4 br[2][2];
    auto issue = [&](int k0, int s) {
        ar[s][0] = *(const intx4*)(ap + k0);
        ar[s][1] = *(const intx4*)(ap + k0 + 8);
        br[s][0] = ((const float4*)(wp + k0))[0];
        br[s][1] = ((const float4*)(wp + k0))[1];
    };
    auto commit = [&](int s, int buf) {
        *(intx4*)&As[buf][srow][scol]     = ar[s][0];
        *(intx4*)&As[buf][srow][scol + 8] = ar[s][1];
        *(short8*)&Bs[buf][brow][bcol]    = cvt8v(br[s][0], br[s][1]);
    };

    floatx4 acc[4][2];
#pragma unroll
    for (int i = 0; i < 4; ++i)
#pragma unroll
        for (int j = 0; j < 2; ++j) acc[i][j] = {0.f, 0.f, 0.f, 0.f};

    issue(0, 0);
    commit(0, 0);
    issue(32, 1);
    __syncthreads();
    for (int i = 0; i < 16; ++i) {
        const int k0 = i * 32;
        const int cur = i & 1;
        if (k0 + 64 < 512) issue(k0 + 64, cur);
        short8 af[4], bf[2];
#pragma unroll
        for (int mt = 0; mt < 4; ++mt) af[mt] = *(const short8*)&As[cur][wr * 64 + mt * 16 + lm][lq * 8];
#pragma unroll
        for (int nt = 0; nt < 2; ++nt) bf[nt] = *(const short8*)&Bs[cur][wc * 32 + nt * 16 + lm][lq * 8];
#pragma unroll
        for (int mt = 0; mt < 4; ++mt)
#pragma unroll
            for (int nt = 0; nt < 2; ++nt)
                acc[mt][nt] = MFMA16(af[mt], bf[nt], acc[mt][nt]);
        if (k0 + 32 < 512) {
            commit(cur ^ 1, cur ^ 1);
            __syncthreads();
        }
    }

#pragma unroll
    for (int nt = 0; nt < 2; ++nt) {
        const int gcol = be + wc * 32 + nt * 16 + lm;
        const float bv = bias[gcol];
#pragma unroll
        for (int mt = 0; mt < 4; ++mt) {
#pragma unroll
            for (int r = 0; r < 4; ++r) {
                int grow = bm + wr * 64 + mt * 16 + lq * 4 + r;
                y[(size_t)grow * 512 + gcol] = acc[mt][nt][r] + bv;
            }
        }
    }
}

extern "C" void kernel_launch(void* const* d_in, const int* in_sizes, int n_in,
                              void* d_out, int out_size, void* d_ws, size_t ws_size,
                              hipStream_t stream) {
    const float* x     = (const float*)d_in[0];
    const float* w_qkv = (const float*)d_in[1];
    const float* w_out = (const float*)d_in[2];
    const float* b_out = (const float*)d_in[3];

    const size_t HEAD_ELEMS = (size_t)16 * 4096 * 64;
    bf16* qw  = (bf16*)d_ws;
    bf16* kw  = qw + HEAD_ELEMS;
    bf16* vtw = kw + HEAD_ELEMS;
    bf16* aw  = vtw + HEAD_ELEMS;
    float* y  = (float*)d_out;

    qkv_gemm<<<dim3(64, 12), 256, 0, stream>>>(x, w_qkv, qw, kw, vtw);
    flash_attn<<<dim3(32, 16), 256, 0, stream>>>(qw, kw, vtw, aw);
    out_gemm<<<dim3(64, 8), 256, 0, stream>>>(aw, w_out, b_out, y);
}

// Round 11
// 192.284 us; speedup vs baseline: 1.2798x; 1.2798x over previous
//
#include <hip/hip_runtime.h>
#include <hip/hip_bf16.h>

typedef __hip_bfloat16 bf16;
typedef __attribute__((ext_vector_type(8))) short short8;
typedef __attribute__((ext_vector_type(4))) short shortx4;
typedef __attribute__((ext_vector_type(4))) float floatx4;
typedef __attribute__((ext_vector_type(4))) int intx4;

#define MFMA16(a, b, c) __builtin_amdgcn_mfma_f32_16x16x32_bf16((a), (b), (c), 0, 0, 0)
#define EXP2(x) __builtin_amdgcn_exp2f(x)

__device__ __forceinline__ short f2s(float v) {
    return __builtin_bit_cast(short, __float2bfloat16(v));
}

// pack two fp32 as truncated bf16 pair {lo, hi} with a single v_perm_b32
__device__ __forceinline__ int packhi(float lo, float hi) {
    return (int)__builtin_amdgcn_perm(__builtin_bit_cast(unsigned, hi),
                                      __builtin_bit_cast(unsigned, lo),
                                      0x07060302u);
}

// convert 8 fp32 (two float4 already in regs) to packed bf16 short8
__device__ __forceinline__ short8 cvt8v(float4 f0, float4 f1) {
    short8 r;
    r[0] = f2s(f0.x); r[1] = f2s(f0.y); r[2] = f2s(f0.z); r[3] = f2s(f0.w);
    r[4] = f2s(f1.x); r[5] = f2s(f1.y); r[6] = f2s(f1.z); r[7] = f2s(f1.w);
    return r;
}

// ---------------------------------------------------------------------------
// Kernel 0: one-pass fp32 -> bf16 conversion of x, w_qkv, w_out.
// The GEMMs re-read these arrays 12-64x; halving their bytes halves the
// bandwidth-bound GEMM time. 655360 threads x 8 floats.
// ---------------------------------------------------------------------------
__global__ __launch_bounds__(256) void cvt_inputs(
    const float* __restrict__ x, const float* __restrict__ wq,
    const float* __restrict__ wo, bf16* __restrict__ xb,
    bf16* __restrict__ wqb, bf16* __restrict__ wob)
{
    int idx = blockIdx.x * 256 + threadIdx.x;   // chunk of 8 floats
    const float* src;
    bf16* dst;
    int off;
    if (idx < 524288)      { src = x;  dst = xb;  off = idx; }
    else if (idx < 622592) { src = wq; dst = wqb; off = idx - 524288; }
    else                   { src = wo; dst = wob; off = idx - 622592; }
    float4 f0 = ((const float4*)src)[off * 2];
    float4 f1 = ((const float4*)src)[off * 2 + 1];
    *(short8*)&((short*)dst)[off * 8] = cvt8v(f0, f1);
}

// ---------------------------------------------------------------------------
// Kernel 1: qkv = x @ w_qkv^T, 128x128 tile, bf16 inputs, LDS ping-pong.
//   q: [bh][n][d] PRE-SCALED by C;  k: [bh][n][d]
//   vt:[bh][d][n j-permuted per 64-tile] (slot u holds logical j = pi(u))
//   All epilogues LDS-staged -> 16B coalesced global writes.
// ---------------------------------------------------------------------------
__global__ __launch_bounds__(256) void qkv_gemm(
    const bf16* __restrict__ xb, const bf16* __restrict__ wqb,
    bf16* __restrict__ q, bf16* __restrict__ k, bf16* __restrict__ vt)
{
    __shared__ short pool[20480];               // 40KB: As/Bs dbuf U Qt/Vt
    short (*As)[128][40] = (short(*)[128][40])pool;
    short (*Bs)[128][40] = (short(*)[128][40])(pool + 10240);
    short (*Qt)[144] = (short(*)[144])pool;     // 128 x 128 (+16 pad)
    short (*Vt)[136] = (short(*)[136])pool;
    const int t = threadIdx.x;
    const int bm = blockIdx.x * 128;
    const int be = blockIdx.y * 128;
    const int w = t >> 6, lane = t & 63, lq = lane >> 4, lm = lane & 15;
    const int wr = w >> 1, wc = w & 1;
    const int srow = t >> 1, scol = (t & 1) * 16;
    const float C = 0.18033688011112042f;

    const bf16* xp = &xb[(size_t)(bm + srow) * 512 + scol];
    const bf16* wp = &wqb[(size_t)(be + srow) * 512 + scol];

    intx4 xr[2], wr4[2];
    auto issue = [&](int k0) {
        xr[0] = *(const intx4*)(xp + k0);
        xr[1] = *(const intx4*)(xp + k0 + 8);
        wr4[0] = *(const intx4*)(wp + k0);
        wr4[1] = *(const intx4*)(wp + k0 + 8);
    };
    auto commit = [&](int buf) {
        *(intx4*)&As[buf][srow][scol]     = xr[0];
        *(intx4*)&As[buf][srow][scol + 8] = xr[1];
        *(intx4*)&Bs[buf][srow][scol]     = wr4[0];
        *(intx4*)&Bs[buf][srow][scol + 8] = wr4[1];
    };

    floatx4 acc[4][4];
#pragma unroll
    for (int i = 0; i < 4; ++i)
#pragma unroll
        for (int j = 0; j < 4; ++j) acc[i][j] = {0.f, 0.f, 0.f, 0.f};

    issue(0);
    commit(0);
    __syncthreads();
    int cur = 0;
    for (int k0 = 0; k0 < 512; k0 += 32) {
        const bool more = (k0 + 32) < 512;
        if (more) issue(k0 + 32);
        short8 af[4], bf[4];
#pragma unroll
        for (int mt = 0; mt < 4; ++mt) af[mt] = *(const short8*)&As[cur][wr * 64 + mt * 16 + lm][lq * 8];
#pragma unroll
        for (int nt = 0; nt < 4; ++nt) bf[nt] = *(const short8*)&Bs[cur][wc * 64 + nt * 16 + lm][lq * 8];
#pragma unroll
        for (int mt = 0; mt < 4; ++mt)
#pragma unroll
            for (int nt = 0; nt < 4; ++nt)
                acc[mt][nt] = MFMA16(af[mt], bf[nt], acc[mt][nt]);
        if (more) {
            commit(cur ^ 1);
            __syncthreads();
        }
        cur ^= 1;
    }

    const int which = be >> 9;     // block-uniform
    __syncthreads();               // all waves done reading As/Bs
    if (which < 2) {
        // q/k: b16-scatter tile into LDS, then 128B-contiguous writeout
        const float scale = (which == 0) ? C : 1.0f;
#pragma unroll
        for (int nt = 0; nt < 4; ++nt) {
            const int e_loc = wc * 64 + nt * 16 + lm;
#pragma unroll
            for (int mt = 0; mt < 4; ++mt)
#pragma unroll
                for (int r = 0; r < 4; ++r)
                    Qt[wr * 64 + mt * 16 + lq * 4 + r][e_loc] = f2s(acc[mt][nt][r] * scale);
        }
        __syncthreads();
        bf16* dst = (which == 0) ? q : k;
        const int tr = t >> 1, th = t & 1;
        const int grow = bm + tr;
        const int b = grow >> 12, n = grow & 4095;
        const int h = ((be + th * 64) & 511) >> 6;
        bf16* p = dst + ((size_t)(b * 8 + h) * 4096 + n) * 64;
#pragma unroll
        for (int c = 0; c < 8; ++c)
            *(intx4*)&p[c * 8] = *(const intx4*)&Qt[tr][th * 64 + c * 8];
    } else {
        // v: stage with pi^-1 applied to n, coalesced writeout along n
#pragma unroll
        for (int nt = 0; nt < 4; ++nt) {
            const int e_loc = wc * 64 + nt * 16 + lm;
#pragma unroll
            for (int mt = 0; mt < 4; ++mt) {
                const int col = wr * 64 + 4 * (mt & 1) + 8 * lq + 32 * (mt >> 1);
                shortx4 v4;
#pragma unroll
                for (int r = 0; r < 4; ++r) v4[r] = f2s(acc[mt][nt][r]);
                *(shortx4*)&Vt[e_loc][col] = v4;
            }
        }
        __syncthreads();
        const int b = bm >> 12, n0 = bm & 4095;
        const int h0 = (be - 1024) >> 6;
        const int row = t >> 1, cb = (t & 1) * 64;
        const int h = h0 + (row >> 6), d = row & 63;
        const size_t gb = ((size_t)(b * 8 + h) * 64 + d) * 4096 + n0 + cb;
#pragma unroll
        for (int c = 0; c < 8; ++c)
            *(intx4*)&vt[gb + c * 8] = *(const intx4*)&Vt[row][cb + c * 8];
    }
}

// ---------------------------------------------------------------------------
// Kernel 2: flash attention, S^T form, no online max, BM=128,
// 1-deep register prefetch + LDS ping-pong (R9 structure — 2-deep regressed).
// ---------------------------------------------------------------------------
__global__ __launch_bounds__(256, 2) void flash_attn(
    const bf16* __restrict__ q, const bf16* __restrict__ k,
    const bf16* __restrict__ vt, bf16* __restrict__ out)
{
    __shared__ short Qs[128][72];
    __shared__ short Ks[2][64][72];
    __shared__ short Vs[2][64][72];   // Vs[.][d][k_phys] (j pre-permuted)
    const int t = threadIdx.x;
    const int i0 = blockIdx.x * 128;
    const int bh = blockIdx.y;
    const int w = t >> 6, lane = t & 63, lq = lane >> 4, lm = lane & 15;
    const floatx4 zero4 = {0.f, 0.f, 0.f, 0.f};

    const size_t nbase = (size_t)bh * 4096 * 64;
    const size_t vbase = (size_t)bh * 64 * 4096;
    const int r0 = t >> 3, c0 = (t & 7) * 8;

#pragma unroll
    for (int it = 0; it < 4; ++it) {
        int off = it * 2048 + t * 8;
        int row = off >> 6, col = off & 63;
        *(intx4*)&Qs[row][col] = *(const intx4*)&q[nbase + (size_t)(i0 + row) * 64 + col];
    }

    intx4 kreg[2], vreg[2];
    auto issue = [&](int j0n) {
        kreg[0] = *(const intx4*)&k[nbase + (size_t)(j0n + r0) * 64 + c0];
        kreg[1] = *(const intx4*)&k[nbase + (size_t)(j0n + 32 + r0) * 64 + c0];
        vreg[0] = *(const intx4*)&vt[vbase + (size_t)r0 * 4096 + j0n + c0];
        vreg[1] = *(const intx4*)&vt[vbase + (size_t)(32 + r0) * 4096 + j0n + c0];
    };
    auto commit = [&](int buf) {
        *(intx4*)&Ks[buf][r0][c0]      = kreg[0];
        *(intx4*)&Ks[buf][32 + r0][c0] = kreg[1];
        *(intx4*)&Vs[buf][r0][c0]      = vreg[0];
        *(intx4*)&Vs[buf][32 + r0][c0] = vreg[1];
    };

    issue(0);
    commit(0);
    __syncthreads();   // covers Qs too
    short8 aq0[2], aq1[2];
#pragma unroll
    for (int g = 0; g < 2; ++g) {
        aq0[g] = *(const short8*)&Qs[g * 64 + w * 16 + lm][lq * 8];
        aq1[g] = *(const short8*)&Qs[g * 64 + w * 16 + lm][32 + lq * 8];
    }

    float l_lane[2] = {0.f, 0.f};
    floatx4 o_acc[2][4];
#pragma unroll
    for (int g = 0; g < 2; ++g)
#pragma unroll
        for (int dt = 0; dt < 4; ++dt) o_acc[g][dt] = zero4;

    int cur = 0;
    for (int j0 = 0; j0 < 4096; j0 += 64) {
        const bool more = (j0 + 64) < 4096;
        if (more) issue(j0 + 64);

        // S^T = K Q~^T: K A-frags shared across the 2 row-groups
        floatx4 s[2][4];
#pragma unroll
        for (int jt = 0; jt < 4; ++jt) {
            short8 bk0 = *(const short8*)&Ks[cur][jt * 16 + lm][lq * 8];
            short8 bk1 = *(const short8*)&Ks[cur][jt * 16 + lm][32 + lq * 8];
#pragma unroll
            for (int g = 0; g < 2; ++g) {
                s[g][jt] = MFMA16(bk0, aq0[g], zero4);
                s[g][jt] = MFMA16(bk1, aq1[g], s[g][jt]);
            }
        }

        // P = exp2(s), truncated pack; l per-lane
        short8 bp0[2], bp1[2];
#pragma unroll
        for (int g = 0; g < 2; ++g) {
            intx4 pkA, pkB;
#pragma unroll
            for (int jt = 0; jt < 4; ++jt) {
                float e0 = EXP2(s[g][jt][0]);
                float e1 = EXP2(s[g][jt][1]);
                float e2 = EXP2(s[g][jt][2]);
                float e3 = EXP2(s[g][jt][3]);
                l_lane[g] += (e0 + e1) + (e2 + e3);
                if (jt < 2) {
                    pkA[jt * 2]     = packhi(e0, e1);
                    pkA[jt * 2 + 1] = packhi(e2, e3);
                } else {
                    pkB[(jt - 2) * 2]     = packhi(e0, e1);
                    pkB[(jt - 2) * 2 + 1] = packhi(e2, e3);
                }
            }
            bp0[g] = __builtin_bit_cast(short8, pkA);
            bp1[g] = __builtin_bit_cast(short8, pkB);
        }

        // O^T += Vt P^T: V A-frags shared across groups
#pragma unroll
        for (int dt = 0; dt < 4; ++dt) {
            short8 av0 = *(const short8*)&Vs[cur][dt * 16 + lm][lq * 8];
            short8 av1 = *(const short8*)&Vs[cur][dt * 16 + lm][32 + lq * 8];
#pragma unroll
            for (int g = 0; g < 2; ++g) {
                o_acc[g][dt] = MFMA16(av0, bp0[g], o_acc[g][dt]);
                o_acc[g][dt] = MFMA16(av1, bp1[g], o_acc[g][dt]);
            }
        }

        if (more) {
            commit(cur ^ 1);     // vmcnt wait lands here, after compute
            __syncthreads();
        }
        cur ^= 1;
    }

    // epilogue per group: l-reduce, O^T -> LDS transpose -> coalesced writes
    const int b = bh >> 3, h = bh & 7;
    short* Os = (short*)Qs;
    const int obase = w * 1024;
    const int il = lane >> 2, c = (lane & 3) * 16;
#pragma unroll
    for (int g = 0; g < 2; ++g) {
        float l = l_lane[g];
        l += __shfl_xor(l, 16);
        l += __shfl_xor(l, 32);
        const float inv_l = 1.0f / l;
        __syncthreads();
#pragma unroll
        for (int dt = 0; dt < 4; ++dt)
#pragma unroll
            for (int r = 0; r < 4; ++r)
                Os[obase + lm * 64 + dt * 16 + lq * 4 + r] = f2s(o_acc[g][dt][r] * inv_l);
        __syncthreads();
        const int i = i0 + g * 64 + w * 16 + il;
        intx4 v0 = *(const intx4*)&Os[obase + il * 64 + c];
        intx4 v1 = *(const intx4*)&Os[obase + il * 64 + c + 8];
        *(intx4*)&out[((size_t)b * 4096 + i) * 512 + h * 64 + c] = v0;
        *(intx4*)&out[((size_t)b * 4096 + i) * 512 + h * 64 + c + 8] = v1;
    }
}

// ---------------------------------------------------------------------------
// Kernel 3: y = attn_out @ w_out^T + b_out, 128x64 tile, bf16 inputs,
// 1-deep prefetch + LDS ping-pong.   (fp32 OUTPUT)
// ---------------------------------------------------------------------------
__global__ __launch_bounds__(256) void out_gemm(
    const bf16* __restrict__ a, const bf16* __restrict__ wob,
    const float* __restrict__ bias, float* __restrict__ y)
{
    __shared__ short As[2][128][40];
    __shared__ short Bs[2][64][40];
    const int t = threadIdx.x;
    const int bm = blockIdx.x * 128;
    const int be = blockIdx.y * 64;
    const int w = t >> 6, lane = t & 63, lq = lane >> 4, lm = lane & 15;
    const int wr = w >> 1, wc = w & 1;
    const int srow = t >> 1, scol = (t & 1) * 16;
    const int brow = t >> 2, bcol = (t & 3) * 8;

    const bf16* ap = &a[(size_t)(bm + srow) * 512 + scol];
    const bf16* wp = &wob[(size_t)(be + brow) * 512 + bcol];

    intx4 ar[2], br;
    auto issue = [&](int k0) {
        ar[0] = *(const intx4*)(ap + k0);
        ar[1] = *(const intx4*)(ap + k0 + 8);
        br    = *(const intx4*)(wp + k0);
    };
    auto commit = [&](int buf) {
        *(intx4*)&As[buf][srow][scol]     = ar[0];
        *(intx4*)&As[buf][srow][scol + 8] = ar[1];
        *(intx4*)&Bs[buf][brow][bcol]     = br;
    };

    floatx4 acc[4][2];
#pragma unroll
    for (int i = 0; i < 4; ++i)
#pragma unroll
        for (int j = 0; j < 2; ++j) acc[i][j] = {0.f, 0.f, 0.f, 0.f};

    issue(0);
    commit(0);
    __syncthreads();
    int cur = 0;
    for (int k0 = 0; k0 < 512; k0 += 32) {
        const bool more = (k0 + 32) < 512;
        if (more) issue(k0 + 32);
        short8 af[4], bf[2];
#pragma unroll
        for (int mt = 0; mt < 4; ++mt) af[mt] = *(const short8*)&As[cur][wr * 64 + mt * 16 + lm][lq * 8];
#pragma unroll
        for (int nt = 0; nt < 2; ++nt) bf[nt] = *(const short8*)&Bs[cur][wc * 32 + nt * 16 + lm][lq * 8];
#pragma unroll
        for (int mt = 0; mt < 4; ++mt)
#pragma unroll
            for (int nt = 0; nt < 2; ++nt)
                acc[mt][nt] = MFMA16(af[mt], bf[nt], acc[mt][nt]);
        if (more) {
            commit(cur ^ 1);
            __syncthreads();
        }
        cur ^= 1;
    }

#pragma unroll
    for (int nt = 0; nt < 2; ++nt) {
        const int gcol = be + wc * 32 + nt * 16 + lm;
        const float bv = bias[gcol];
#pragma unroll
        for (int mt = 0; mt < 4; ++mt) {
#pragma unroll
            for (int r = 0; r < 4; ++r) {
                int grow = bm + wr * 64 + mt * 16 + lq * 4 + r;
                y[(size_t)grow * 512 + gcol] = acc[mt][nt][r] + bv;
            }
        }
    }
}

extern "C" void kernel_launch(void* const* d_in, const int* in_sizes, int n_in,
                              void* d_out, int out_size, void* d_ws, size_t ws_size,
                              hipStream_t stream) {
    const float* x     = (const float*)d_in[0];
    const float* w_qkv = (const float*)d_in[1];
    const float* w_out = (const float*)d_in[2];
    const float* b_out = (const float*)d_in[3];

    const size_t HEAD_ELEMS = (size_t)16 * 4096 * 64;  // 4,194,304
    bf16* qw  = (bf16*)d_ws;
    bf16* kw  = qw + HEAD_ELEMS;
    bf16* vtw = kw + HEAD_ELEMS;
    bf16* aw  = vtw + HEAD_ELEMS;
    bf16* xb  = aw + HEAD_ELEMS;
    bf16* wqb = xb + (size_t)8192 * 512;
    bf16* wob = wqb + (size_t)1536 * 512;
    float* y  = (float*)d_out;

    cvt_inputs<<<2560, 256, 0, stream>>>(x, w_qkv, w_out, xb, wqb, wob);
    qkv_gemm<<<dim3(64, 12), 256, 0, stream>>>(xb, wqb, qw, kw, vtw);
    flash_attn<<<dim3(32, 16), 256, 0, stream>>>(qw, kw, vtw, aw);
    out_gemm<<<dim3(64, 8), 256, 0, stream>>>(aw, wob, b_out, y);
}